// Round 12
// baseline (324.690 us; speedup 1.0000x reference)
//
#include <hip/hip_runtime.h>

#define NN 50000
#define NE 800000
#define CAP 64         // per-dst bucket capacity; Poisson(16) P(>64) ~ 1e-18
#define KC 72          // 576/8 k-chunks

typedef __bf16 bf16x8 __attribute__((ext_vector_type(8)));
typedef float f32x4 __attribute__((ext_vector_type(4)));
typedef float f32x2 __attribute__((ext_vector_type(2)));
typedef unsigned short ushort;
typedef unsigned int uint;

typedef __attribute__((address_space(1))) const void GAS;
typedef __attribute__((address_space(3))) void LAS;

__device__ inline ushort f2bf(float x) {  // RNE float->bf16
  uint u = __builtin_bit_cast(uint, x);
  u += 0x7FFF + ((u >> 16) & 1);
  return (ushort)(u >> 16);
}
__device__ inline float bf2f(ushort u) {
  return __builtin_bit_cast(float, (uint)u << 16);
}

// ---------------- merged build (R8 form): scatter + fbf + weight/comp pack ---
// blocks [0,3125): scatter, 1 edge/thread (max TLP for the atomic chain)
// blocks [3125,6250): features f32->bf16
// blocks [6250,6394): W0; [6394,6538): W1; [6538,6574): W2; [6574,6576): cpad

__device__ inline void wprep_body(const float* __restrict__ basis,
                                  const float* __restrict__ loopw,
                                  ushort* __restrict__ W2, int DOUT, int NCOLS,
                                  int idx) {
  int total = KC * NCOLS * 8;
  if (idx >= total) return;
  int j = idx & 7;
  int n = (idx >> 3) % NCOLS;
  int kc = idx / (8 * NCOLS);
  int k = kc * 8 + j;
  float v = 0.f;
  if (n < DOUT) v = (k < 512) ? basis[k * DOUT + n] : loopw[(k - 512) * DOUT + n];
  W2[((size_t)kc * NCOLS + n) * 8 + j] = f2bf(v);
}

__global__ __launch_bounds__(256) void build_kernel(
    const int* __restrict__ dstv, const int* __restrict__ srcv,
    const int* __restrict__ etv, int* __restrict__ cursor, int* __restrict__ pk,
    const float* __restrict__ f, ushort* __restrict__ fb,
    const float* __restrict__ b0, const float* __restrict__ l0, ushort* __restrict__ W0,
    const float* __restrict__ b1, const float* __restrict__ l1, ushort* __restrict__ W1,
    const float* __restrict__ b2, const float* __restrict__ l2, ushort* __restrict__ W2,
    const float* __restrict__ c0, const float* __restrict__ c1,
    const float* __restrict__ c2, float* __restrict__ cp) {
  int blk = blockIdx.x;
  int tid = threadIdx.x;
  if (blk < 3125) {
    int i = blk * 256 + tid;  // NE = 3125*256 exactly
    int d = dstv[i];
    int p = atomicAdd(&cursor[d], 1);
    if (p < CAP) pk[d * CAP + p] = (etv[i] << 16) | srcv[i];
  } else if (blk < 6250) {
    int i = (blk - 3125) * 256 + tid;  // NN*16 = 800000 ushort4 granules
    float4 v = ((const float4*)f)[i];
    ushort4 u;
    u.x = f2bf(v.x); u.y = f2bf(v.y); u.z = f2bf(v.z); u.w = f2bf(v.w);
    ((ushort4*)fb)[i] = u;
  } else if (blk < 6394) {
    wprep_body(b0, l0, W0, 64, 64, (blk - 6250) * 256 + tid);
  } else if (blk < 6538) {
    wprep_body(b1, l1, W1, 64, 64, (blk - 6394) * 256 + tid);
  } else if (blk < 6574) {
    wprep_body(b2, l2, W2, 8, 16, (blk - 6538) * 256 + tid);
  } else {
    // cpad[3][17][8]: per-layer comp + zero sentinel row 16
    int idx = (blk - 6574) * 256 + tid;  // 0..511
    if (idx < 408) {
      int l = idx / 136, k = idx % 136;
      const float* src = (l == 0) ? c0 : ((l == 1) ? c1 : c2);
      cp[idx] = (k < 128) ? src[k] : 0.f;
    }
  }
}

// ---------------- fused layer: async-staged agg + MFMA dense ----------------
// 512 threads = 8 waves; 16 dsts/block (2 per wave, serial).
// Phase A per 16-edge chunk: 8x global_load_lds pair-loads (lanes 0-31 ->
// even edge row, 32-63 -> odd edge row; LDS dest base+lane*4 lands both rows
// contiguously). These are async & vmcnt-counted -> compiler CANNOT serialize
// the flight. One s_waitcnt vmcnt(0) per chunk, then consume from LDS with
// ds_read_u16 + cvt + 4x v_pk_fma_f32. Masked tail edges -> comp row 16
// (zeros), src 0 (harmless load).
// LDS X [kc][m^(kc&7)][8] bf16 (XOR swizzle, conflict-free both phases).
// Phase B (waves 0..3 / wave 0): swapped-operand mfma_16x16x32_bf16, A=W2,B=X.

template <int DOUT, int NCOLS, bool OBF>
__global__ __launch_bounds__(512, 4) void layer_kernel(
    const ushort* __restrict__ hb,     // [NN,64] bf16
    const float* __restrict__ cpad,    // [17,8] f32 (row 16 = zeros)
    const int* __restrict__ degv,
    const int* __restrict__ pk,        // [NN,CAP]
    const ushort* __restrict__ W2,     // [KC][NCOLS][8] bf16
    const float* __restrict__ bias,    // [DOUT]
    void* __restrict__ outp,           // [NN,DOUT] bf16 (OBF) or f32
    float slope)
{
  __shared__ ushort X[KC][16][8];      // 18432 B
  __shared__ ushort STG[8][16][64];    // 16384 B staging: [wave][edge][feat]
  int tid = threadIdx.x;
  int wave = tid >> 6;                 // 0..7
  int lane = tid & 63;
  int dbase = blockIdx.x * 16;         // grid 3125 * 16 = NN exactly

  for (int t = 0; t < 2; ++t) {
    int dl = wave * 2 + t;             // local X row 0..15
    int d = __builtin_amdgcn_readfirstlane(dbase + dl);
    int deg = degv[d];
    int dwu = __builtin_amdgcn_readfirstlane(deg > CAP ? CAP : deg);
    const int4* p4 = (const int4*)(pk + (size_t)d * CAP);

    f32x2 acc2[4] = {{0.f, 0.f}, {0.f, 0.f}, {0.f, 0.f}, {0.f, 0.f}};
    for (int base = 0; base < dwu; base += 16) {
      int4 g0 = p4[(base >> 2) + 0];
      int4 g1 = p4[(base >> 2) + 1];
      int4 g2 = p4[(base >> 2) + 2];
      int4 g3 = p4[(base >> 2) + 3];
      int pe[16] = {g0.x, g0.y, g0.z, g0.w, g1.x, g1.y, g1.z, g1.w,
                    g2.x, g2.y, g2.z, g2.w, g3.x, g3.y, g3.z, g3.w};
      uint rs[16], ss[16];
#pragma unroll
      for (int i = 0; i < 16; ++i) {
        uint up = (uint)__builtin_amdgcn_readfirstlane(pe[i]);
        int valid = (base + i) < dwu;        // wave-uniform scalar select
        rs[i] = valid ? (up >> 16) : 16u;    // -> zero comp row
        ss[i] = valid ? (up & 0xFFFFu) : 0u; // -> harmless in-bounds load
      }
      // issue 8 async pair-loads: 16 edge rows in flight
#pragma unroll
      for (int i = 0; i < 8; ++i) {
        uint s_sel = (lane < 32) ? ss[2 * i] : ss[2 * i + 1];
        const ushort* gp = hb + (size_t)s_sel * 64 + (lane & 31) * 2;
        __builtin_amdgcn_global_load_lds((GAS*)gp, (LAS*)&STG[wave][2 * i][0],
                                         4, 0, 0);
      }
      asm volatile("s_waitcnt vmcnt(0)" ::: "memory");
      __builtin_amdgcn_sched_barrier(0);
      // consume
#pragma unroll
      for (int i = 0; i < 16; ++i) {
        float hv = bf2f(STG[wave][i][lane]);
        f32x2 h2 = {hv, hv};
        const f32x2* c2 = (const f32x2*)(cpad + rs[i] * 8);
#pragma unroll
        for (int j = 0; j < 4; ++j)
          acc2[j] = __builtin_elementwise_fma(c2[j], h2, acc2[j]);
      }
    }

    float inv = 1.0f / (float)(deg > 1 ? deg : 1);
    int jj = lane & 7;
    int csub = lane >> 3;
#pragma unroll
    for (int b = 0; b < 8; ++b) {
      float v = ((b & 1) ? acc2[b >> 1].y : acc2[b >> 1].x) * inv;
      X[b * 8 + csub][dl ^ csub][jj] = f2bf(v);   // row XOR swizzle (kc&7==csub)
    }
    X[64 + csub][dl ^ csub][jj] = hb[(size_t)d * 64 + lane];  // self-loop input
  }
  __syncthreads();

  // ---- Phase B ----
  if (wave < (DOUT == 64 ? 4 : 1)) {
    int q = lane >> 4;
    int r = lane & 15;
    f32x4 accd = {0.f, 0.f, 0.f, 0.f};
#pragma unroll
    for (int ks = 0; ks < 18; ++ks) {
      int kc = ks * 4 + q;
      bf16x8 bfrag = *(const bf16x8*)&X[kc][r ^ (kc & 7)][0];
      bf16x8 afrag = *(const bf16x8*)(W2 + ((size_t)kc * NCOLS + wave * 16 + r) * 8);
      accd = __builtin_amdgcn_mfma_f32_16x16x32_bf16(afrag, bfrag, accd, 0, 0, 0);
    }
    int m = dbase + r;
    int nb = wave * 16 + q * 4;
    if (nb < DOUT) {
      float4 bv = *(const float4*)(bias + nb);
      float v0 = accd[0] + bv.x;
      float v1 = accd[1] + bv.y;
      float v2 = accd[2] + bv.z;
      float v3 = accd[3] + bv.w;
      v0 = v0 > 0.f ? v0 : slope * v0;
      v1 = v1 > 0.f ? v1 : slope * v1;
      v2 = v2 > 0.f ? v2 : slope * v2;
      v3 = v3 > 0.f ? v3 : slope * v3;
      if (OBF) {
        ushort4 u;
        u.x = f2bf(v0); u.y = f2bf(v1); u.z = f2bf(v2); u.w = f2bf(v3);
        *(ushort4*)((ushort*)outp + (size_t)m * DOUT + nb) = u;
      } else {
        *(float4*)((float*)outp + (size_t)m * DOUT + nb) = float4{v0, v1, v2, v3};
      }
    }
  }
}

// ---------------- launch ----------------

extern "C" void kernel_launch(void* const* d_in, const int* in_sizes, int n_in,
                              void* d_out, int out_size, void* d_ws, size_t ws_size,
                              hipStream_t stream) {
  const float* features = (const float*)d_in[0];
  const float* basis0   = (const float*)d_in[2];
  const float* comp0    = (const float*)d_in[3];
  const float* loop0    = (const float*)d_in[4];
  const float* bias0    = (const float*)d_in[5];
  const float* basis1   = (const float*)d_in[6];
  const float* comp1    = (const float*)d_in[7];
  const float* loop1    = (const float*)d_in[8];
  const float* bias1    = (const float*)d_in[9];
  const float* basis2   = (const float*)d_in[10];
  const float* comp2    = (const float*)d_in[11];
  const float* loop2    = (const float*)d_in[12];
  const float* bias2    = (const float*)d_in[13];
  const int* etypes     = (const int*)d_in[14];
  const int* srcv       = (const int*)d_in[15];
  const int* dstv       = (const int*)d_in[16];

  char* ws = (char*)d_ws;
  size_t off = 0;
  auto alloc = [&](size_t bytes) {
    void* p = ws + off;
    off += (bytes + 255) & ~(size_t)255;
    return p;
  };
  int* cnt      = (int*)alloc(NN * sizeof(int));
  int* pk       = (int*)alloc((size_t)NN * CAP * sizeof(int));
  ushort* W2_0  = (ushort*)alloc((size_t)KC * 64 * 8 * sizeof(ushort));
  ushort* W2_1  = (ushort*)alloc((size_t)KC * 64 * 8 * sizeof(ushort));
  ushort* W2_2  = (ushort*)alloc((size_t)KC * 16 * 8 * sizeof(ushort));
  float* cpad   = (float*)alloc(3 * 136 * sizeof(float));
  ushort* fbf   = (ushort*)alloc((size_t)NN * 64 * sizeof(ushort));
  ushort* hA    = (ushort*)alloc((size_t)NN * 64 * sizeof(ushort));
  ushort* hB    = (ushort*)alloc((size_t)NN * 64 * sizeof(ushort));

  hipMemsetAsync(cnt, 0, NN * sizeof(int), stream);
  build_kernel<<<6576, 256, 0, stream>>>(dstv, srcv, etypes, cnt, pk,
                                         features, fbf,
                                         basis0, loop0, W2_0,
                                         basis1, loop1, W2_1,
                                         basis2, loop2, W2_2,
                                         comp0, comp1, comp2, cpad);

  layer_kernel<64, 64, true><<<3125, 512, 0, stream>>>(
      fbf, cpad + 0 * 136, cnt, pk, W2_0, bias0, hA, 0.01f);
  layer_kernel<64, 64, true><<<3125, 512, 0, stream>>>(
      hA, cpad + 1 * 136, cnt, pk, W2_1, bias1, hB, 0.01f);
  layer_kernel<8, 16, false><<<3125, 512, 0, stream>>>(
      hB, cpad + 2 * 136, cnt, pk, W2_2, bias2, d_out, 0.0f);
}

// Round 13
// 169.712 us; speedup vs baseline: 1.9132x; 1.9132x over previous
//
#include <hip/hip_runtime.h>

#define NN 50000
#define NE 800000
#define CAP 64         // per-dst bucket capacity; Poisson(16) P(>64) ~ 1e-18
#define KC 72          // 576/8 k-chunks
#define RNG 6250       // NN/8, dst range per XCD slice
#define EPB 2047       // edges scanned per scatter block (391*2047 >= NE)

typedef __bf16 bf16x8 __attribute__((ext_vector_type(8)));
typedef float f32x4 __attribute__((ext_vector_type(4)));
typedef float f32x2 __attribute__((ext_vector_type(2)));
typedef unsigned short ushort;
typedef unsigned int uint;

__device__ inline ushort f2bf(float x) {  // RNE float->bf16
  uint u = __builtin_bit_cast(uint, x);
  u += 0x7FFF + ((u >> 16) & 1);
  return (ushort)(u >> 16);
}
__device__ inline float bf2f(ushort u) {
  return __builtin_bit_cast(float, (uint)u << 16);
}

// ---------------- merged build: XCD-partitioned scatter + fbf + packs --------
// blocks [0,3128): scatter — 8 dst-ranges x 391 blocks. Block (sub, sel=blk&7)
//   scans edge slice [sub*EPB, ...) and handles only dst in [sel*RNG,(sel+1)*RNG).
//   With blockIdx%8 -> XCD round-robin, cursor atomics and pk stores become
//   XCD-L2-local: no cross-XCD line ping-pong (the R8 build's 55MB write churn).
// blocks [3128,6253): features f32->bf16
// blocks [6253,6397): W0; [6397,6541): W1; [6541,6577): W2; [6577,6579): cpad

__device__ inline void wprep_body(const float* __restrict__ basis,
                                  const float* __restrict__ loopw,
                                  ushort* __restrict__ W2, int DOUT, int NCOLS,
                                  int idx) {
  int total = KC * NCOLS * 8;
  if (idx >= total) return;
  int j = idx & 7;
  int n = (idx >> 3) % NCOLS;
  int kc = idx / (8 * NCOLS);
  int k = kc * 8 + j;
  float v = 0.f;
  if (n < DOUT) v = (k < 512) ? basis[k * DOUT + n] : loopw[(k - 512) * DOUT + n];
  W2[((size_t)kc * NCOLS + n) * 8 + j] = f2bf(v);
}

__global__ __launch_bounds__(256) void build_kernel(
    const int* __restrict__ dstv, const int* __restrict__ srcv,
    const int* __restrict__ etv, int* __restrict__ cursor, int* __restrict__ pk,
    const float* __restrict__ f, ushort* __restrict__ fb,
    const float* __restrict__ b0, const float* __restrict__ l0, ushort* __restrict__ W0,
    const float* __restrict__ b1, const float* __restrict__ l1, ushort* __restrict__ W1,
    const float* __restrict__ b2, const float* __restrict__ l2, ushort* __restrict__ W2,
    const float* __restrict__ c0, const float* __restrict__ c1,
    const float* __restrict__ c2, float* __restrict__ cp) {
  int blk = blockIdx.x;
  int tid = threadIdx.x;
  if (blk < 3128) {
    int sel = blk & 7;
    int sub = blk >> 3;          // 0..390
    int lo = sel * RNG;
    int start = sub * EPB;
    for (int t = tid; t < EPB; t += 256) {
      int i = start + t;
      if (i >= NE) break;
      int d = dstv[i];
      if ((uint)(d - lo) < (uint)RNG) {
        int p = atomicAdd(&cursor[d], 1);
        if (p < CAP) pk[d * CAP + p] = (etv[i] << 16) | srcv[i];
      }
    }
  } else if (blk < 6253) {
    int i = (blk - 3128) * 256 + tid;  // NN*16 = 800000 ushort4 granules
    if (i < NN * 16) {
      float4 v = ((const float4*)f)[i];
      ushort4 u;
      u.x = f2bf(v.x); u.y = f2bf(v.y); u.z = f2bf(v.z); u.w = f2bf(v.w);
      ((ushort4*)fb)[i] = u;
    }
  } else if (blk < 6397) {
    wprep_body(b0, l0, W0, 64, 64, (blk - 6253) * 256 + tid);
  } else if (blk < 6541) {
    wprep_body(b1, l1, W1, 64, 64, (blk - 6397) * 256 + tid);
  } else if (blk < 6577) {
    wprep_body(b2, l2, W2, 8, 16, (blk - 6541) * 256 + tid);
  } else {
    // cpad[3][17][8]: per-layer comp + zero sentinel row 16
    int idx = (blk - 6577) * 256 + tid;  // 0..511
    if (idx < 408) {
      int l = idx / 136, k = idx % 136;
      const float* src = (l == 0) ? c0 : ((l == 1) ? c1 : c2);
      cp[idx] = (k < 128) ? src[k] : 0.f;
    }
  }
}

// ---------------- fused layer (R10 form): agg + MFMA dense ------------------
// 16 waves, 1 dst each. Phase A: 8-edge flight (2 int4 pk groups, hv[8]),
// invalid slots masked wave-uniformly to sentinel comp row 16 (zeros).
// Accumulate f32x2 -> v_pk_fma_f32. LDS X [kc][m^(kc&7)][8] bf16 XOR swizzle
// (conflict-free both phases). Phase B: swapped-operand mfma_16x16x32_bf16.

template <int DOUT, int NCOLS, bool OBF>
__global__ __launch_bounds__(1024, 8) void layer_kernel(
    const ushort* __restrict__ hb,     // [NN,64] bf16
    const float* __restrict__ cpad,    // [17,8] f32 (row 16 = zeros)
    const int* __restrict__ degv,
    const int* __restrict__ pk,        // [NN,CAP]
    const ushort* __restrict__ W2,     // [KC][NCOLS][8] bf16
    const float* __restrict__ bias,    // [DOUT]
    void* __restrict__ outp,           // [NN,DOUT] bf16 (OBF) or f32
    float slope)
{
  __shared__ ushort X[KC][16][8];  // 18432 B
  int tid = threadIdx.x;
  int wave = tid >> 6;
  int lane = tid & 63;
  int dbase = blockIdx.x * 16;     // grid 3125 * 16 = NN exactly
  int d = __builtin_amdgcn_readfirstlane(dbase + wave);

  // ---- Phase A ----
  int deg = degv[d];
  int dw = deg > CAP ? CAP : deg;
  const int4* p4 = (const int4*)(pk + (size_t)d * CAP);

  f32x2 acc2[4] = {{0.f, 0.f}, {0.f, 0.f}, {0.f, 0.f}, {0.f, 0.f}};
  for (int base = 0; base < dw; base += 8) {
    int qg = base >> 3;
    int4 e0 = p4[qg * 2];
    int4 e1 = p4[qg * 2 + 1];     // always in-bounds (CAP/4 groups)
    int pe[8] = {e0.x, e0.y, e0.z, e0.w, e1.x, e1.y, e1.z, e1.w};
    float hv[8];
    int ps[8];
#pragma unroll
    for (int i = 0; i < 8; ++i) {
      int pr = __builtin_amdgcn_readfirstlane(pe[i]);
      ps[i] = (base + i < dw) ? pr : (16 << 16);  // wave-uniform mask -> sentinel
      hv[i] = bf2f(hb[(size_t)(ps[i] & 0xFFFF) * 64 + lane]);
    }
#pragma unroll
    for (int i = 0; i < 8; ++i) {
      const f32x2* c2 = (const f32x2*)(cpad + (ps[i] >> 16) * 8);
      f32x2 h2 = {hv[i], hv[i]};
#pragma unroll
      for (int j = 0; j < 4; ++j)
        acc2[j] = __builtin_elementwise_fma(c2[j], h2, acc2[j]);
    }
  }

  float inv = 1.0f / (float)(deg > 1 ? deg : 1);
  int jj = lane & 7;
  int csub = lane >> 3;
#pragma unroll
  for (int b = 0; b < 8; ++b) {
    float v = ((b & 1) ? acc2[b >> 1].y : acc2[b >> 1].x) * inv;
    X[b * 8 + csub][wave ^ csub][jj] = f2bf(v);   // row XOR swizzle (kc&7 == csub)
  }
  X[64 + csub][wave ^ csub][jj] = hb[(size_t)d * 64 + lane];  // self-loop input
  __syncthreads();

  // ---- Phase B ----
  if (wave < (DOUT == 64 ? 4 : 1)) {
    int q = lane >> 4;
    int r = lane & 15;
    f32x4 accd = {0.f, 0.f, 0.f, 0.f};
#pragma unroll
    for (int ks = 0; ks < 18; ++ks) {
      int kc = ks * 4 + q;
      bf16x8 bfrag = *(const bf16x8*)&X[kc][r ^ (kc & 7)][0];
      bf16x8 afrag = *(const bf16x8*)(W2 + ((size_t)kc * NCOLS + wave * 16 + r) * 8);
      accd = __builtin_amdgcn_mfma_f32_16x16x32_bf16(afrag, bfrag, accd, 0, 0, 0);
    }
    int m = dbase + r;
    int nb = wave * 16 + q * 4;
    if (nb < DOUT) {
      float4 bv = *(const float4*)(bias + nb);
      float v0 = accd[0] + bv.x;
      float v1 = accd[1] + bv.y;
      float v2 = accd[2] + bv.z;
      float v3 = accd[3] + bv.w;
      v0 = v0 > 0.f ? v0 : slope * v0;
      v1 = v1 > 0.f ? v1 : slope * v1;
      v2 = v2 > 0.f ? v2 : slope * v2;
      v3 = v3 > 0.f ? v3 : slope * v3;
      if (OBF) {
        ushort4 u;
        u.x = f2bf(v0); u.y = f2bf(v1); u.z = f2bf(v2); u.w = f2bf(v3);
        *(ushort4*)((ushort*)outp + (size_t)m * DOUT + nb) = u;
      } else {
        *(float4*)((float*)outp + (size_t)m * DOUT + nb) = float4{v0, v1, v2, v3};
      }
    }
  }
}

// ---------------- launch ----------------

extern "C" void kernel_launch(void* const* d_in, const int* in_sizes, int n_in,
                              void* d_out, int out_size, void* d_ws, size_t ws_size,
                              hipStream_t stream) {
  const float* features = (const float*)d_in[0];
  const float* basis0   = (const float*)d_in[2];
  const float* comp0    = (const float*)d_in[3];
  const float* loop0    = (const float*)d_in[4];
  const float* bias0    = (const float*)d_in[5];
  const float* basis1   = (const float*)d_in[6];
  const float* comp1    = (const float*)d_in[7];
  const float* loop1    = (const float*)d_in[8];
  const float* bias1    = (const float*)d_in[9];
  const float* basis2   = (const float*)d_in[10];
  const float* comp2    = (const float*)d_in[11];
  const float* loop2    = (const float*)d_in[12];
  const float* bias2    = (const float*)d_in[13];
  const int* etypes     = (const int*)d_in[14];
  const int* srcv       = (const int*)d_in[15];
  const int* dstv       = (const int*)d_in[16];

  char* ws = (char*)d_ws;
  size_t off = 0;
  auto alloc = [&](size_t bytes) {
    void* p = ws + off;
    off += (bytes + 255) & ~(size_t)255;
    return p;
  };
  int* cnt      = (int*)alloc(NN * sizeof(int));
  int* pk       = (int*)alloc((size_t)NN * CAP * sizeof(int));
  ushort* W2_0  = (ushort*)alloc((size_t)KC * 64 * 8 * sizeof(ushort));
  ushort* W2_1  = (ushort*)alloc((size_t)KC * 64 * 8 * sizeof(ushort));
  ushort* W2_2  = (ushort*)alloc((size_t)KC * 16 * 8 * sizeof(ushort));
  float* cpad   = (float*)alloc(3 * 136 * sizeof(float));
  ushort* fbf   = (ushort*)alloc((size_t)NN * 64 * sizeof(ushort));
  ushort* hA    = (ushort*)alloc((size_t)NN * 64 * sizeof(ushort));
  ushort* hB    = (ushort*)alloc((size_t)NN * 64 * sizeof(ushort));

  hipMemsetAsync(cnt, 0, NN * sizeof(int), stream);
  build_kernel<<<6579, 256, 0, stream>>>(dstv, srcv, etypes, cnt, pk,
                                         features, fbf,
                                         basis0, loop0, W2_0,
                                         basis1, loop1, W2_1,
                                         basis2, loop2, W2_2,
                                         comp0, comp1, comp2, cpad);

  layer_kernel<64, 64, true><<<3125, 1024, 0, stream>>>(
      fbf, cpad + 0 * 136, cnt, pk, W2_0, bias0, hA, 0.01f);
  layer_kernel<64, 64, true><<<3125, 1024, 0, stream>>>(
      hA, cpad + 1 * 136, cnt, pk, W2_1, bias1, hB, 0.01f);
  layer_kernel<8, 16, false><<<3125, 1024, 0, stream>>>(
      hB, cpad + 2 * 136, cnt, pk, W2_2, bias2, d_out, 0.0f);
}